// Round 1
// baseline (63.946 us; speedup 1.0000x reference)
//
#include <hip/hip_runtime.h>

// MultiEnhanceGroupFusionHead:
//   4x grouped 7x7 xcorr (SAME pad) -> *0.001 -> concat(32ch) -> 1x1 conv(128) -> global avg pool
// Mean commutes with conv: only 49 clipped-rectangle sums R per (n,ch) map are needed.
// out[n,o] = b[o] + (0.001/4096) * sum_c W[o,c] * sum_m sum_taps z_l[n, 32*oc+m, tap] * R[n, 32*oc+m, tap]
//   with c = l*8 + oc.

__global__ __launch_bounds__(256) void xcorr_mean_kernel(
    const float* __restrict__ x,
    const float* __restrict__ z0, const float* __restrict__ z1,
    const float* __restrict__ z2, const float* __restrict__ z3,
    float* __restrict__ P)  // [16384][4] per-map per-level tap-dot
{
    const int map = blockIdx.x;          // n*256 + ch
    const int t = threadIdx.x;
    const float4* xv = reinterpret_cast<const float4*>(x + (size_t)map * 4096);

    // Each thread loads 4 float4s: float idx = k*1024 + 4t.
    // col = (4t) & 63 (fixed per thread), row = k*16 + t/16.
    float4 v0 = xv[t];
    float4 v1 = xv[256 + t];
    float4 v2 = xv[512 + t];
    float4 v3 = xv[768 + t];

    __shared__ float rowpart[6][16];   // rows 0,1,2,61,62,63 partial sums (per col-group)
    __shared__ float colpart[6][16];   // cols 0,1,2,61,62,63 partial sums (per row-group)
    __shared__ float corner[6][6];     // raw x at rows{0,1,2,61,62,63} x cols{0,1,2,61,62,63}
    __shared__ float rowsum[6], colsum[6];
    __shared__ float Twave[4];
    __shared__ float Tval;
    __shared__ float Rtab[49];

    float cs0 = v0.x + v1.x + v2.x + v3.x;
    float cs1 = v0.y + v1.y + v2.y + v3.y;
    float cs2 = v0.z + v1.z + v2.z + v3.z;
    float cs3 = v0.w + v1.w + v2.w + v3.w;
    float tot = cs0 + cs1 + cs2 + cs3;

    const int g = t >> 4;     // row within k-chunk (row = k*16 + g)
    const int c16 = t & 15;   // col group (cols 4*c16 .. 4*c16+3)

    if (g < 3) {  // k=0 -> rows 0..2
        rowpart[g][c16] = v0.x + v0.y + v0.z + v0.w;
        if (c16 == 0)  { corner[g][0] = v0.x; corner[g][1] = v0.y; corner[g][2] = v0.z; }
        if (c16 == 15) { corner[g][3] = v0.y; corner[g][4] = v0.z; corner[g][5] = v0.w; }
    }
    if (g >= 13) { // k=3 -> rows 61..63 (row = 48+g)
        const int r = g - 13;
        rowpart[3 + r][c16] = v3.x + v3.y + v3.z + v3.w;
        if (c16 == 0)  { corner[3+r][0] = v3.x; corner[3+r][1] = v3.y; corner[3+r][2] = v3.z; }
        if (c16 == 15) { corner[3+r][3] = v3.y; corner[3+r][4] = v3.z; corner[3+r][5] = v3.w; }
    }
    if (c16 == 0)  { colpart[0][g] = cs0; colpart[1][g] = cs1; colpart[2][g] = cs2; }
    if (c16 == 15) { colpart[3][g] = cs1; colpart[4][g] = cs2; colpart[5][g] = cs3; }

    // total: wave reduce then cross-wave
    float wsum = tot;
    #pragma unroll
    for (int off = 32; off; off >>= 1) wsum += __shfl_down(wsum, off);
    if ((t & 63) == 0) Twave[t >> 6] = wsum;
    __syncthreads();

    if (t == 0) Tval = Twave[0] + Twave[1] + Twave[2] + Twave[3];
    if (t < 6) {
        float s = 0.f;
        #pragma unroll
        for (int i = 0; i < 16; ++i) s += rowpart[t][i];
        rowsum[t] = s;
    } else if (t >= 8 && t < 14) {
        float s = 0.f;
        #pragma unroll
        for (int i = 0; i < 16; ++i) s += colpart[t - 8][i];
        colsum[t - 8] = s;
    }
    __syncthreads();

    if (t < 49) {
        const int dy = t / 7, dx = t % 7;
        const int oy = dy - 3, ox = dx - 3;
        const int ty = oy > 0 ? oy : 0, by = oy < 0 ? -oy : 0;
        const int lx = ox > 0 ? ox : 0, rx = ox < 0 ? -ox : 0;
        float R = Tval;
        for (int i = 0; i < ty; ++i) R -= rowsum[i];       // top rows 0..ty-1
        for (int i = 0; i < by; ++i) R -= rowsum[5 - i];   // bottom rows 63,62,..
        for (int i = 0; i < lx; ++i) R -= colsum[i];
        for (int i = 0; i < rx; ++i) R -= colsum[5 - i];
        for (int a = 0; a < ty; ++a) {
            for (int b = 0; b < lx; ++b) R += corner[a][b];
            for (int b = 0; b < rx; ++b) R += corner[a][5 - b];
        }
        for (int a = 0; a < by; ++a) {
            for (int b = 0; b < lx; ++b) R += corner[5 - a][b];
            for (int b = 0; b < rx; ++b) R += corner[5 - a][5 - b];
        }
        Rtab[t] = R;
    }
    __syncthreads();

    // 4 waves: wave wv computes the 49-tap dot with z_{wv} for this map
    const int wv = t >> 6, lane = t & 63;
    const float* zl = (wv == 0) ? z0 : (wv == 1) ? z1 : (wv == 2) ? z2 : z3;
    float val = 0.f;
    if (lane < 49) val = zl[(size_t)map * 49 + lane] * Rtab[lane];
    #pragma unroll
    for (int off = 32; off; off >>= 1) val += __shfl_down(val, off);
    if (lane == 0) P[map * 4 + wv] = val;
}

__global__ __launch_bounds__(128) void fuse_kernel(
    const float* __restrict__ P,   // [64*256][4]
    const float* __restrict__ W,   // [128][32] (merged_w[:,:,0,0])
    const float* __restrict__ B,   // [128]
    float* __restrict__ out)       // [64][128]
{
    const int n = blockIdx.x;
    const int t = threadIdx.x;
    __shared__ float S[32];
    if (t < 32) {
        const int l = t >> 3, oc = t & 7;   // concat channel c = l*8 + oc
        float s = 0.f;
        const float* p = P + ((size_t)n * 256 + oc * 32) * 4 + l;
        #pragma unroll
        for (int m = 0; m < 32; ++m) s += p[m * 4];
        S[t] = s;
    }
    __syncthreads();
    const float scale = 0.001f / 4096.0f;   // OUT_SCALE / (H*W)
    float acc = 0.f;
    const float* wr = W + t * 32;
    #pragma unroll
    for (int c = 0; c < 32; ++c) acc += wr[c] * S[c];
    out[n * 128 + t] = fmaf(acc, scale, B[t]);
}

extern "C" void kernel_launch(void* const* d_in, const int* in_sizes, int n_in,
                              void* d_out, int out_size, void* d_ws, size_t ws_size,
                              hipStream_t stream) {
    const float* z0 = (const float*)d_in[0];
    const float* z1 = (const float*)d_in[1];
    const float* z2 = (const float*)d_in[2];
    const float* z3 = (const float*)d_in[3];
    const float* x  = (const float*)d_in[4];
    const float* Wm = (const float*)d_in[5];
    const float* Bm = (const float*)d_in[6];
    float* out = (float*)d_out;
    float* P = (float*)d_ws;   // 16384*4 floats = 256 KB scratch

    hipLaunchKernelGGL(xcorr_mean_kernel, dim3(64 * 256), dim3(256), 0, stream,
                       x, z0, z1, z2, z3, P);
    hipLaunchKernelGGL(fuse_kernel, dim3(64), dim3(128), 0, stream, Wm ? P : P, Wm, Bm, out);
}

// Round 2
// 51.836 us; speedup vs baseline: 1.2336x; 1.2336x over previous
//
#include <hip/hip_runtime.h>

// MultiEnhanceGroupFusionHead:
//   4x grouped 7x7 xcorr (SAME pad) -> *0.001 -> concat(32ch) -> 1x1 conv(128) -> global avg pool
// Mean commutes with conv: only 49 clipped-rectangle sums R per (n,ch) map are needed:
//   R[oy,ox] = Total - (boundary row strips) - (boundary col strips) + (corner overlaps)
// out[n,o] = b[o] + (0.001/4096) * sum_c W[o,c] * sum_m sum_taps z_l[n,32*oc+m,tap] * R[n,32*oc+m,tap]
//
// Round 2: one WAVE per map (was one block). 16 float4 loads/lane (4x MLP),
// wave-parallel shuffle reductions, 4 parallel 16-lane tap-dot groups.

__global__ __launch_bounds__(256) void xcorr_mean_wave(
    const float* __restrict__ x,
    const float* __restrict__ z0, const float* __restrict__ z1,
    const float* __restrict__ z2, const float* __restrict__ z3,
    float* __restrict__ P)  // [16384][4]
{
    const int wave = threadIdx.x >> 6;
    const int l    = threadIdx.x & 63;
    const int map  = blockIdx.x * 4 + wave;          // n*256 + ch

    // Lane l, round k: float4 index k*64 + l  ->  row = k*4 + (l>>4), cols 4*(l&15)..+3
    const float4* __restrict__ xv = reinterpret_cast<const float4*>(x) + (size_t)map * 1024;

    float4 v[16];
    #pragma unroll
    for (int k = 0; k < 16; ++k) v[k] = xv[k * 64 + l];

    // per-lane column partials (lane's 4 cols are fixed across rounds)
    float cs0 = 0.f, cs1 = 0.f, cs2 = 0.f, cs3 = 0.f;
    #pragma unroll
    for (int k = 0; k < 16; ++k) { cs0 += v[k].x; cs1 += v[k].y; cs2 += v[k].z; cs3 += v[k].w; }

    // boundary-row partials: round 0 holds rows 0..3, round 15 holds rows 60..63
    float rp_lo = v[0].x + v[0].y + v[0].z + v[0].w;
    float rp_hi = v[15].x + v[15].y + v[15].z + v[15].w;

    // full column sums: reduce across the 4 row-subgroups (xor 16,32)
    #pragma unroll
    for (int off = 16; off < 64; off <<= 1) {
        cs0 += __shfl_xor(cs0, off);
        cs1 += __shfl_xor(cs1, off);
        cs2 += __shfl_xor(cs2, off);
        cs3 += __shfl_xor(cs3, off);
    }
    // total: sum this lane's 4 full col-sums, reduce across 16 col-groups
    float tot = cs0 + cs1 + cs2 + cs3;
    #pragma unroll
    for (int off = 1; off < 16; off <<= 1) tot += __shfl_xor(tot, off);

    // boundary row sums: reduce within each 16-lane group (xor 1..8)
    #pragma unroll
    for (int off = 1; off < 16; off <<= 1) {
        rp_lo += __shfl_xor(rp_lo, off);
        rp_hi += __shfl_xor(rp_hi, off);
    }

    // Per-wave LDS scratch: [0..5] rowsum(0,1,2,61,62,63), [8..13] colsum(0,1,2,61,62,63),
    // [16+6a+b] corner[a][b], [60] total, [64..112] Rtab
    __shared__ float sm[4][128];
    float* s = sm[wave];
    const int g = l >> 4, cg = l & 15;

    if (cg == 0) {
        if (g < 3)  s[g] = rp_lo;                    // rows 0,1,2
        if (g >= 1) s[2 + g] = rp_hi;                // rows 61,62,63
        if (g == 0) { s[8] = cs0; s[9] = cs1; s[10] = cs2; }   // cols 0,1,2
    }
    if (cg == 15 && g == 0) { s[11] = cs1; s[12] = cs2; s[13] = cs3; }  // cols 61,62,63

    {   // corners: raw x at rows{0,1,2,61,62,63} x cols{0,1,2,61,62,63}
        const float4 a = v[0], b = v[15];
        if (cg == 0) {
            if (g < 3)  { s[16 + 6*g + 0] = a.x; s[16 + 6*g + 1] = a.y; s[16 + 6*g + 2] = a.z; }
            if (g >= 1) { const int r = 2 + g;
                          s[16 + 6*r + 0] = b.x; s[16 + 6*r + 1] = b.y; s[16 + 6*r + 2] = b.z; }
        }
        if (cg == 15) {
            if (g < 3)  { s[16 + 6*g + 3] = a.y; s[16 + 6*g + 4] = a.z; s[16 + 6*g + 5] = a.w; }
            if (g >= 1) { const int r = 2 + g;
                          s[16 + 6*r + 3] = b.y; s[16 + 6*r + 4] = b.z; s[16 + 6*r + 5] = b.w; }
        }
    }
    if (l == 0) s[60] = tot;
    __syncthreads();

    // 49 clipped-rectangle sums
    if (l < 49) {
        const int dy = l / 7, dx = l % 7;
        const int oy = dy - 3, ox = dx - 3;
        const int ty = oy > 0 ? oy : 0, by = oy < 0 ? -oy : 0;
        const int lx = ox > 0 ? ox : 0, rx = ox < 0 ? -ox : 0;
        float R = s[60];
        for (int i = 0; i < ty; ++i) R -= s[i];          // top rows 0..ty-1
        for (int i = 0; i < by; ++i) R -= s[5 - i];      // bottom rows 63,62,..
        for (int i = 0; i < lx; ++i) R -= s[8 + i];      // left cols
        for (int i = 0; i < rx; ++i) R -= s[13 - i];     // right cols
        for (int a = 0; a < ty; ++a) {
            for (int b = 0; b < lx; ++b) R += s[16 + 6*a + b];
            for (int b = 0; b < rx; ++b) R += s[16 + 6*a + (5 - b)];
        }
        for (int a = 0; a < by; ++a) {
            for (int b = 0; b < lx; ++b) R += s[16 + 6*(5 - a) + b];
            for (int b = 0; b < rx; ++b) R += s[16 + 6*(5 - a) + (5 - b)];
        }
        s[64 + l] = R;
    }
    __syncthreads();

    // 4 parallel 16-lane groups: group g dots Rtab with z_g for this map
    const float* zl = (g == 0) ? z0 : (g == 1) ? z1 : (g == 2) ? z2 : z3;
    const float* zp = zl + (size_t)map * 49;
    float acc = 0.f;
    #pragma unroll
    for (int j = 0; j < 4; ++j) {
        const int t = cg + 16 * j;
        if (t < 49) acc += zp[t] * s[64 + t];
    }
    #pragma unroll
    for (int off = 1; off < 16; off <<= 1) acc += __shfl_xor(acc, off);
    if (cg == 0) P[map * 4 + g] = acc;
}

__global__ __launch_bounds__(128) void fuse_kernel(
    const float* __restrict__ P,   // [64*256][4]
    const float* __restrict__ W,   // [128][32] (merged_w[:,:,0,0])
    const float* __restrict__ B,   // [128]
    float* __restrict__ out)       // [64][128]
{
    const int n = blockIdx.x;
    const int t = threadIdx.x;
    __shared__ float S[32];
    if (t < 32) {
        const int l = t >> 3, oc = t & 7;   // concat channel c = l*8 + oc
        float s = 0.f;
        const float* p = P + ((size_t)n * 256 + oc * 32) * 4 + l;
        #pragma unroll
        for (int m = 0; m < 32; ++m) s += p[m * 4];
        S[t] = s;
    }
    __syncthreads();
    const float scale = 0.001f / 4096.0f;   // OUT_SCALE / (H*W)
    float acc = 0.f;
    const float* wr = W + t * 32;
    #pragma unroll
    for (int c = 0; c < 32; ++c) acc += wr[c] * S[c];
    out[n * 128 + t] = fmaf(acc, scale, B[t]);
}

extern "C" void kernel_launch(void* const* d_in, const int* in_sizes, int n_in,
                              void* d_out, int out_size, void* d_ws, size_t ws_size,
                              hipStream_t stream) {
    const float* z0 = (const float*)d_in[0];
    const float* z1 = (const float*)d_in[1];
    const float* z2 = (const float*)d_in[2];
    const float* z3 = (const float*)d_in[3];
    const float* x  = (const float*)d_in[4];
    const float* Wm = (const float*)d_in[5];
    const float* Bm = (const float*)d_in[6];
    float* out = (float*)d_out;
    float* P = (float*)d_ws;   // 16384*4 floats = 256 KB scratch

    hipLaunchKernelGGL(xcorr_mean_wave, dim3(4096), dim3(256), 0, stream,
                       x, z0, z1, z2, z3, P);
    hipLaunchKernelGGL(fuse_kernel, dim3(64), dim3(128), 0, stream, P, Wm, Bm, out);
}